// Round 6
// baseline (316.277 us; speedup 1.0000x reference)
//
#include <hip/hip_runtime.h>

// QattenNet: B=E*T=8192, S=256, A=32, O=128, QH1=128, QD=64, C1=128, H=4.
// R9: R8 post-mortem — VALUBusy*dur ~= 11us ~= FMA floor: the MLP's VALU work
// is already minimal; it is LATENCY-bound at 16 waves/CU (every round so far
// ran launch_bounds(...,4) = 4 blocks/CU, inherited from R3 unexamined).
// Manual prefetch (R8) regressed; revert it. This round: occupancy-first.
//  - launch_bounds(256,8) -> 8 blocks/CU (32 waves/CU), VGPR cap 64
//    (phase tiles sized 2rx4c / 1rx2c / 1rx4c, ~45 VGPR, no manual prefetch).
//  - LDS 16.1 KB: NB=8, s_lds (dead after phase 2) unioned with emb_lds.
//  - Two-role even/odd interleave: grid 2048 = one resident generation,
//    each CU holds ~4 MLP + ~4 stream blocks concurrently throughout.
//  - B-role / prep / final verbatim from the measured-best R5 kernel.

static constexpr int Sd  = 256;
static constexpr int Ad  = 32;
static constexpr int Od  = 128;
static constexpr int QDd = 64;
static constexpr int NB  = 8;
static constexpr int A_BLOCKS = 1024;   // 8192 / NB
static constexpr int B_BLOCKS = 1024;   // 8192 / 8 rows per block

__global__ void qatten_prep(const float* __restrict__ Wk, const float* __restrict__ bk,
                            float* __restrict__ WkT, float* __restrict__ bkSum)
{
    int idx = blockIdx.x * 256 + threadIdx.x;   // 0..8191
    int k = idx >> 7;          // 0..63
    int o = idx & 127;         // 0..127
    float s = 0.f;
#pragma unroll
    for (int h = 0; h < 4; ++h) s += Wk[h * (Od * QDd) + o * QDd + k];
    WkT[k * Od + o] = s;
    if (idx < QDd) {
        float t = 0.f;
#pragma unroll
        for (int h = 0; h < 4; ++h) t += bk[h * QDd + idx];
        bkSum[idx] = t;
    }
}

union SEmb {
    float s[NB][Sd];        // 8 KB, live phases 0-2
    float emb[NB][68];      // 2.125 KB, live phases 3-5
};

__global__ __launch_bounds__(256, 8) void qatten_main(
    const float* __restrict__ qv, const float* __restrict__ st, const float* __restrict__ fs,
    const float* __restrict__ Wq1, const float* __restrict__ bq1,
    const float* __restrict__ Wq2, const float* __restrict__ bq2,
    const float* __restrict__ Wc1, const float* __restrict__ bc1,
    const float* __restrict__ Wc2, const float* __restrict__ bc2,
    const float* __restrict__ WkT, const float* __restrict__ bkSum,
    float* __restrict__ v_out, float* __restrict__ bias_out, float* __restrict__ g_out)
{
    __shared__ SEmb u;                  // 8 KB
    __shared__ float h_lds[NB][260];    // 8.125 KB (cols 0-127: h1, 128-255: hc)
                                        // total 16.1 KB -> 8 blocks/CU

    const int tid = threadIdx.x;
    const int bid = blockIdx.x;

    if ((bid & 1) == 0) {
        // ================= A-role: MLP -> v, bias =================
        const int b0 = (bid >> 1) * NB;

        // ---- stage s (8x256): 2 float4 per thread, coalesced ----
        {
            const float4* sp = (const float4*)(st + (size_t)b0 * Sd);
            float4* sl = (float4*)&u.s[0][0];
            sl[tid]       = sp[tid];
            sl[tid + 256] = sp[tid + 256];
        }
        __syncthreads();

        // ---- phase 2: h = relu(s @ [Wq1|Wc1] + [bq1|bc1]) ----
        // thread = 2 rows x 4 cols; per 4-k chunk: 4 coalesced float4 weight
        // loads + 2 float4 LDS broadcasts -> 32 FMA. No manual prefetch.
        {
            const int wg = tid & 63;                 // col group: cols 4wg..4wg+3
            const int rg = (tid >> 6) << 1;          // rows rg, rg+1 (wave-uniform)
            const float* __restrict__ Wb = (wg < 32) ? (Wq1 + 4 * wg)
                                                     : (Wc1 + 4 * (wg - 32));
            const float4 bb4 = (wg < 32) ? *(const float4*)&bq1[4 * wg]
                                         : *(const float4*)&bc1[4 * (wg - 32)];
            float acc[2][4];
#pragma unroll
            for (int r = 0; r < 2; ++r)
#pragma unroll
                for (int c = 0; c < 4; ++c) acc[r][c] = 0.f;

            for (int k = 0; k < Sd; k += 4) {
                float w[4][4];
#pragma unroll
                for (int kk = 0; kk < 4; ++kk) {
                    const float4 t = *(const float4*)&Wb[(size_t)(k + kk) * 128];
                    w[kk][0] = t.x; w[kk][1] = t.y; w[kk][2] = t.z; w[kk][3] = t.w;
                }
#pragma unroll
                for (int r = 0; r < 2; ++r) {
                    const float4 s4 = *(const float4*)&u.s[rg + r][k];
                    float a0 = acc[r][0], a1 = acc[r][1], a2 = acc[r][2], a3 = acc[r][3];
                    a0 = fmaf(s4.x, w[0][0], a0); a1 = fmaf(s4.x, w[0][1], a1);
                    a2 = fmaf(s4.x, w[0][2], a2); a3 = fmaf(s4.x, w[0][3], a3);
                    a0 = fmaf(s4.y, w[1][0], a0); a1 = fmaf(s4.y, w[1][1], a1);
                    a2 = fmaf(s4.y, w[1][2], a2); a3 = fmaf(s4.y, w[1][3], a3);
                    a0 = fmaf(s4.z, w[2][0], a0); a1 = fmaf(s4.z, w[2][1], a1);
                    a2 = fmaf(s4.z, w[2][2], a2); a3 = fmaf(s4.z, w[2][3], a3);
                    a0 = fmaf(s4.w, w[3][0], a0); a1 = fmaf(s4.w, w[3][1], a1);
                    a2 = fmaf(s4.w, w[3][2], a2); a3 = fmaf(s4.w, w[3][3], a3);
                    acc[r][0] = a0; acc[r][1] = a1; acc[r][2] = a2; acc[r][3] = a3;
                }
            }
#pragma unroll
            for (int r = 0; r < 2; ++r) {
                float4 o;
                o.x = fmaxf(acc[r][0] + bb4.x, 0.f);
                o.y = fmaxf(acc[r][1] + bb4.y, 0.f);
                o.z = fmaxf(acc[r][2] + bb4.z, 0.f);
                o.w = fmaxf(acc[r][3] + bb4.w, 0.f);
                *(float4*)&h_lds[rg + r][4 * wg] = o;
            }
        }
        __syncthreads();   // h ready; u.s dead -> u.emb may be written

        // ---- phase 3: emb = h1 @ Wq2 + bq2; thread = 1 row x 2 cols ----
        {
            const int c2  = tid & 31;       // cols 2c2, 2c2+1 (of 64)
            const int row = tid >> 5;       // 0..7
            float a0 = 0.f, a1 = 0.f;
            for (int k = 0; k < 128; k += 4) {
                float2 w[4];
#pragma unroll
                for (int kk = 0; kk < 4; ++kk)
                    w[kk] = *(const float2*)&Wq2[(size_t)(k + kk) * 64 + 2 * c2];
                const float4 h4 = *(const float4*)&h_lds[row][k];
                a0 = fmaf(h4.x, w[0].x, a0);  a1 = fmaf(h4.x, w[0].y, a1);
                a0 = fmaf(h4.y, w[1].x, a0);  a1 = fmaf(h4.y, w[1].y, a1);
                a0 = fmaf(h4.z, w[2].x, a0);  a1 = fmaf(h4.z, w[2].y, a1);
                a0 = fmaf(h4.w, w[3].x, a0);  a1 = fmaf(h4.w, w[3].y, a1);
            }
            const float2 b2 = *(const float2*)&bq2[2 * c2];
            float2 o; o.x = a0 + b2.x; o.y = a1 + b2.y;
            *(float2*)&u.emb[row][2 * c2] = o;
        }
        __syncthreads();   // emb ready

        // ---- phase 4: v = emb @ WkT; thread = 1 row x 4 cols -> global ----
        {
            const int cg  = tid & 31;       // cols 4cg..4cg+3 (of 128)
            const int row = tid >> 5;       // 0..7
            float acc[4] = {0.f, 0.f, 0.f, 0.f};
            for (int k = 0; k < QDd; k += 4) {
                float w[4][4];
#pragma unroll
                for (int kk = 0; kk < 4; ++kk) {
                    const float4 t = *(const float4*)&WkT[(size_t)(k + kk) * 128 + 4 * cg];
                    w[kk][0] = t.x; w[kk][1] = t.y; w[kk][2] = t.z; w[kk][3] = t.w;
                }
                const float4 e4 = *(const float4*)&u.emb[row][k];
#pragma unroll
                for (int c = 0; c < 4; ++c) {
                    float a = acc[c];
                    a = fmaf(e4.x, w[0][c], a);
                    a = fmaf(e4.y, w[1][c], a);
                    a = fmaf(e4.z, w[2][c], a);
                    a = fmaf(e4.w, w[3][c], a);
                    acc[c] = a;
                }
            }
            float4 o; o.x = acc[0]; o.y = acc[1]; o.z = acc[2]; o.w = acc[3];
            *(float4*)&v_out[(size_t)(b0 + row) * Od + 4 * cg] = o;
        }

        // ---- phase 5: bias[b] = c[b] + beta[b]*sumq[b]; 32 lanes per b ----
        {
            const int b = tid >> 5;         // 0..7
            const int i = tid & 31;
            float pb = 0.f, pc = 0.f;
#pragma unroll
            for (int k = i; k < QDd; k += 32)  pb = fmaf(u.emb[b][k], bkSum[k], pb);
#pragma unroll
            for (int j = i; j < 128; j += 32)  pc = fmaf(h_lds[b][128 + j], Wc2[j], pc);
            float pq = qv[(size_t)(b0 + b) * Ad + i];
#pragma unroll
            for (int d = 16; d >= 1; d >>= 1) {
                pb += __shfl_down(pb, d, 32);
                pc += __shfl_down(pc, d, 32);
                pq += __shfl_down(pq, d, 32);
            }
            if (i == 0) bias_out[b0 + b] = (pc + bc2[0]) + pb * pq;
        }
    } else {
        // ================= B-role: stream fs -> g[b] = sum_a q[b,a]*f[b,a,:] ===
        // 8 rows/block, 2 rows/wave (32 independent 16B loads in flight).
        const int bidx = bid >> 1;              // 0..1023
        const int w = tid >> 6;
        const int l = tid & 63;
        const int r0 = bidx * 8 + w * 2;
        const float4* __restrict__ f0 = (const float4*)fs + (size_t)r0 * (Ad * Od / 4);
        const float4* __restrict__ f1 = f0 + (Ad * Od / 4);
        const float q0 = qv[(size_t)r0 * Ad + (l & 31)];
        const float q1 = qv[(size_t)(r0 + 1) * Ad + (l & 31)];
        float4 a0 = {0.f, 0.f, 0.f, 0.f}, a1 = {0.f, 0.f, 0.f, 0.f};
#pragma unroll
        for (int i = 0; i < 16; ++i) {
            const float4 x0 = f0[i * 64 + l];
            const float4 x1 = f1[i * 64 + l];
            const float qa0 = __shfl(q0, 2 * i + (l >> 5), 64);
            const float qa1 = __shfl(q1, 2 * i + (l >> 5), 64);
            a0.x = fmaf(qa0, x0.x, a0.x);
            a0.y = fmaf(qa0, x0.y, a0.y);
            a0.z = fmaf(qa0, x0.z, a0.z);
            a0.w = fmaf(qa0, x0.w, a0.w);
            a1.x = fmaf(qa1, x1.x, a1.x);
            a1.y = fmaf(qa1, x1.y, a1.y);
            a1.z = fmaf(qa1, x1.z, a1.z);
            a1.w = fmaf(qa1, x1.w, a1.w);
        }
        a0.x += __shfl_xor(a0.x, 32, 64);
        a0.y += __shfl_xor(a0.y, 32, 64);
        a0.z += __shfl_xor(a0.z, 32, 64);
        a0.w += __shfl_xor(a0.w, 32, 64);
        a1.x += __shfl_xor(a1.x, 32, 64);
        a1.y += __shfl_xor(a1.y, 32, 64);
        a1.z += __shfl_xor(a1.z, 32, 64);
        a1.w += __shfl_xor(a1.w, 32, 64);
        if (l < 32) {
            *(float4*)(g_out + (size_t)r0 * Od + l * 4) = a0;
            *(float4*)(g_out + (size_t)(r0 + 1) * Od + l * 4) = a1;
        }
    }
}

__global__ __launch_bounds__(256, 8) void qatten_final(
    const float* __restrict__ g, const float* __restrict__ v,
    const float* __restrict__ bias, float* __restrict__ out)
{
    const int tid = threadIdx.x;
    const int b = blockIdx.x * 8 + (tid >> 5);
    const int i = tid & 31;
    const float4 gv = *(const float4*)(g + (size_t)b * Od + i * 4);
    const float4 vv = *(const float4*)(v + (size_t)b * Od + i * 4);
    float d = gv.x * vv.x;
    d = fmaf(gv.y, vv.y, d);
    d = fmaf(gv.z, vv.z, d);
    d = fmaf(gv.w, vv.w, d);
#pragma unroll
    for (int k = 16; k >= 1; k >>= 1) d += __shfl_down(d, k, 32);
    if (i == 0) out[b] = d + bias[b];
}

extern "C" void kernel_launch(void* const* d_in, const int* in_sizes, int n_in,
                              void* d_out, int out_size, void* d_ws, size_t ws_size,
                              hipStream_t stream) {
    const float* qv  = (const float*)d_in[0];
    const float* st  = (const float*)d_in[1];
    const float* fs  = (const float*)d_in[2];
    const float* Wq1 = (const float*)d_in[3];
    const float* bq1 = (const float*)d_in[4];
    const float* Wq2 = (const float*)d_in[5];
    const float* bq2 = (const float*)d_in[6];
    const float* Wk  = (const float*)d_in[7];
    const float* bk  = (const float*)d_in[8];
    const float* Wc1 = (const float*)d_in[9];
    const float* bc1 = (const float*)d_in[10];
    const float* Wc2 = (const float*)d_in[11];
    const float* bc2 = (const float*)d_in[12];
    float* out = (float*)d_out;

    // workspace (floats): WkT 8192 | bkSum 64 | bias 8192 | v 1048576 | g 1048576
    float* WkT   = (float*)d_ws;
    float* bkSum = WkT + QDd * Od;          // +8192
    float* bias  = bkSum + QDd;             // +64
    float* vbuf  = bias + 8192;             // +8192  (16-B aligned)
    float* gbuf  = vbuf + 8192 * Od;        // +1048576

    qatten_prep<<<32, 256, 0, stream>>>(Wk, bk, WkT, bkSum);
    qatten_main<<<A_BLOCKS + B_BLOCKS, 256, 0, stream>>>(
        qv, st, fs, Wq1, bq1, Wq2, bq2, Wc1, bc1, Wc2, bc2,
        WkT, bkSum, vbuf, bias, gbuf);
    qatten_final<<<1024, 256, 0, stream>>>(gbuf, vbuf, bias, out);
}

// Round 7
// 241.754 us; speedup vs baseline: 1.3083x; 1.3083x over previous
//
#include <hip/hip_runtime.h>

// QattenNet: B=E*T=8192, S=256, A=32, O=128, QH1=128, QD=64, C1=128, H=4.
// R10: re-fit of all rounds: concurrent kernels time ~= max(stream, MLP),
// serial split ~= sum => stream ~= 70-75us (1.9 TB/s effective for 134 MB),
// MLP ~= 35-50us. The STREAM is the wall, not the MLP (R7-R9 attacked the
// wrong component; occupancy/prefetch changes regressed). Stream limiter =
// per-wave MLP depth: consume-as-you-go loop keeps only ~4 float4 loads in
// flight (VGPR 32-64). Fix: issue 16 loads into static register arrays
// before consuming (2 unrolled batches of 8 chunks x 2 rows).
// Everything else byte-identical to the measured-best R5 kernel (242.8us):
// NB=16, A_BLOCKS=512 dispatched first, launch_bounds(256,4), same phases.

static constexpr int Sd  = 256;
static constexpr int Ad  = 32;
static constexpr int Od  = 128;
static constexpr int QDd = 64;
static constexpr int NB  = 16;
static constexpr int A_BLOCKS = 512;    // 8192 / NB
static constexpr int B_BLOCKS = 1024;   // 8192 / 8 rows per block

__global__ void qatten_prep(const float* __restrict__ Wk, const float* __restrict__ bk,
                            float* __restrict__ WkT, float* __restrict__ bkSum)
{
    int idx = blockIdx.x * 256 + threadIdx.x;   // 0..8191
    int k = idx >> 7;          // 0..63
    int o = idx & 127;         // 0..127
    float s = 0.f;
#pragma unroll
    for (int h = 0; h < 4; ++h) s += Wk[h * (Od * QDd) + o * QDd + k];
    WkT[k * Od + o] = s;
    if (idx < QDd) {
        float t = 0.f;
#pragma unroll
        for (int h = 0; h < 4; ++h) t += bk[h * QDd + idx];
        bkSum[idx] = t;
    }
}

__global__ __launch_bounds__(256, 4) void qatten_main(
    const float* __restrict__ qv, const float* __restrict__ st, const float* __restrict__ fs,
    const float* __restrict__ Wq1, const float* __restrict__ bq1,
    const float* __restrict__ Wq2, const float* __restrict__ bq2,
    const float* __restrict__ Wc1, const float* __restrict__ bc1,
    const float* __restrict__ Wc2, const float* __restrict__ bc2,
    const float* __restrict__ WkT, const float* __restrict__ bkSum,
    float* __restrict__ v_out, float* __restrict__ bias_out, float* __restrict__ g_out)
{
    __shared__ float s_lds[NB][Sd];     // 16 KB
    __shared__ float h_lds[NB][260];    // 16.25 KB (cols 0-127: h1, 128-255: hc)
    __shared__ float emb_lds[NB][68];   // 4.25 KB   total ~36.5 KB

    const int tid = threadIdx.x;
    const int bid = blockIdx.x;

    if (bid < A_BLOCKS) {
        // ================= A-role: MLP -> v, bias =================
        const int b0 = bid * NB;

        // ---- stage s (16x256), coalesced: 4 float4 per thread ----
        {
            const float4* sp = (const float4*)(st + (size_t)b0 * Sd);
            float4* sl = (float4*)&s_lds[0][0];
            sl[tid]       = sp[tid];
            sl[tid + 256] = sp[tid + 256];
            sl[tid + 512] = sp[tid + 512];
            sl[tid + 768] = sp[tid + 768];
        }
        __syncthreads();

        // ---- phase 2: h = relu(s @ [Wq1|Wc1] + [bq1|bc1]) ----
        // thread = 4 rows x 4 cols; 4 coalesced float4 weight loads +
        // 4 float4 LDS broadcasts -> 64 FMA per 4-k chunk.
        {
            const int wg = tid & 63;                 // col group: cols 4wg..4wg+3
            const int rg = (tid >> 6) << 2;          // row base: 0,4,8,12
            const float* __restrict__ Wb = (wg < 32) ? (Wq1 + 4 * wg)
                                                     : (Wc1 + 4 * (wg - 32));
            const float4 bb4 = (wg < 32) ? *(const float4*)&bq1[4 * wg]
                                         : *(const float4*)&bc1[4 * (wg - 32)];
            float acc[4][4];
#pragma unroll
            for (int r = 0; r < 4; ++r)
#pragma unroll
                for (int c = 0; c < 4; ++c) acc[r][c] = 0.f;

            for (int k = 0; k < Sd; k += 4) {
                float w[4][4], sv[4][4];
#pragma unroll
                for (int kk = 0; kk < 4; ++kk) {
                    const float4 t = *(const float4*)&Wb[(size_t)(k + kk) * 128];
                    w[kk][0] = t.x; w[kk][1] = t.y; w[kk][2] = t.z; w[kk][3] = t.w;
                }
#pragma unroll
                for (int r = 0; r < 4; ++r) {
                    const float4 t = *(const float4*)&s_lds[rg + r][k];
                    sv[r][0] = t.x; sv[r][1] = t.y; sv[r][2] = t.z; sv[r][3] = t.w;
                }
#pragma unroll
                for (int r = 0; r < 4; ++r)
#pragma unroll
                    for (int kk = 0; kk < 4; ++kk)
#pragma unroll
                        for (int c = 0; c < 4; ++c)
                            acc[r][c] = fmaf(sv[r][kk], w[kk][c], acc[r][c]);
            }
#pragma unroll
            for (int r = 0; r < 4; ++r) {
                float4 o;
                o.x = fmaxf(acc[r][0] + bb4.x, 0.f);
                o.y = fmaxf(acc[r][1] + bb4.y, 0.f);
                o.z = fmaxf(acc[r][2] + bb4.z, 0.f);
                o.w = fmaxf(acc[r][3] + bb4.w, 0.f);
                *(float4*)&h_lds[rg + r][4 * wg] = o;
            }
        }
        __syncthreads();

        // ---- phase 3: emb = h1 @ Wq2 + bq2; thread = 1 row x 4 cols ----
        {
            const int cg = tid & 15;        // cols 4cg..4cg+3 (of 64)
            const int row = tid >> 4;       // 0..15
            float acc[4] = {0.f, 0.f, 0.f, 0.f};
            for (int k = 0; k < 128; k += 4) {
                float w[4][4];
#pragma unroll
                for (int kk = 0; kk < 4; ++kk) {
                    const float4 t = *(const float4*)&Wq2[(size_t)(k + kk) * 64 + 4 * cg];
                    w[kk][0] = t.x; w[kk][1] = t.y; w[kk][2] = t.z; w[kk][3] = t.w;
                }
                const float4 h4 = *(const float4*)&h_lds[row][k];
                float hv[4] = {h4.x, h4.y, h4.z, h4.w};
#pragma unroll
                for (int kk = 0; kk < 4; ++kk)
#pragma unroll
                    for (int c = 0; c < 4; ++c)
                        acc[c] = fmaf(hv[kk], w[kk][c], acc[c]);
            }
            const float4 b4 = *(const float4*)&bq2[4 * cg];
            float4 o;
            o.x = acc[0] + b4.x; o.y = acc[1] + b4.y;
            o.z = acc[2] + b4.z; o.w = acc[3] + b4.w;
            *(float4*)&emb_lds[row][4 * cg] = o;
        }
        __syncthreads();

        // ---- phase 4: v = emb @ WkT; thread = 2 rows x 4 cols ----
        {
            const int cg = tid & 31;              // cols 4cg..4cg+3 (of 128)
            const int rp = (tid >> 5) << 1;       // rows rp, rp+1
            float acc[2][4];
#pragma unroll
            for (int r = 0; r < 2; ++r)
#pragma unroll
                for (int c = 0; c < 4; ++c) acc[r][c] = 0.f;
            for (int k = 0; k < QDd; k += 4) {
                float w[4][4], ev[2][4];
#pragma unroll
                for (int kk = 0; kk < 4; ++kk) {
                    const float4 t = *(const float4*)&WkT[(size_t)(k + kk) * 128 + 4 * cg];
                    w[kk][0] = t.x; w[kk][1] = t.y; w[kk][2] = t.z; w[kk][3] = t.w;
                }
#pragma unroll
                for (int r = 0; r < 2; ++r) {
                    const float4 t = *(const float4*)&emb_lds[rp + r][k];
                    ev[r][0] = t.x; ev[r][1] = t.y; ev[r][2] = t.z; ev[r][3] = t.w;
                }
#pragma unroll
                for (int r = 0; r < 2; ++r)
#pragma unroll
                    for (int kk = 0; kk < 4; ++kk)
#pragma unroll
                        for (int c = 0; c < 4; ++c)
                            acc[r][c] = fmaf(ev[r][kk], w[kk][c], acc[r][c]);
            }
#pragma unroll
            for (int r = 0; r < 2; ++r) {
                float4 o;
                o.x = acc[r][0]; o.y = acc[r][1]; o.z = acc[r][2]; o.w = acc[r][3];
                *(float4*)&v_out[(size_t)(b0 + rp + r) * Od + 4 * cg] = o;
            }
        }

        // ---- phase 5: bias[b] = c[b] + beta[b]*sumq[b]; 16 lanes per b ----
        {
            const int b = tid >> 4;         // 0..15
            const int i = tid & 15;
            float pb = 0.f, pc = 0.f;
#pragma unroll
            for (int k = i; k < QDd; k += 16)  pb = fmaf(emb_lds[b][k], bkSum[k], pb);
#pragma unroll
            for (int j = i; j < 128; j += 16)  pc = fmaf(h_lds[b][128 + j], Wc2[j], pc);
            float pq = qv[(size_t)(b0 + b) * Ad + i] + qv[(size_t)(b0 + b) * Ad + i + 16];
#pragma unroll
            for (int d = 8; d >= 1; d >>= 1) {
                pb += __shfl_down(pb, d, 16);
                pc += __shfl_down(pc, d, 16);
                pq += __shfl_down(pq, d, 16);
            }
            if (i == 0) bias_out[b0 + b] = (pc + bc2[0]) + pb * pq;
        }
    } else {
        // ================= B-role: stream fs -> g[b] = sum_a q[b,a]*f[b,a,:] ===
        // 8 rows/block, 2 rows/wave. DEEP-BATCHED: 16 float4 loads issued into
        // static register arrays before any consumption (2 batches of 8 chunks
        // x 2 rows), so ~16 KB/wave is in flight instead of the compiler's ~4
        // loads. lane l owns float4 slot (l&31); chunk ii covers agents
        // a = 2*ii + (l>>5); each load instr = 64 contiguous float4 = 1 KB.
        const int bidx = bid - A_BLOCKS;        // 0..1023
        const int w = tid >> 6;
        const int l = tid & 63;
        const int r0 = bidx * 8 + w * 2;
        const float4* __restrict__ f0 = (const float4*)fs + (size_t)r0 * (Ad * Od / 4);
        const float4* __restrict__ f1 = f0 + (Ad * Od / 4);
        const float q0 = qv[(size_t)r0 * Ad + (l & 31)];
        const float q1 = qv[(size_t)(r0 + 1) * Ad + (l & 31)];
        float4 a0 = {0.f, 0.f, 0.f, 0.f}, a1 = {0.f, 0.f, 0.f, 0.f};
#pragma unroll
        for (int batch = 0; batch < 2; ++batch) {
            float4 x0[8], x1[8];
#pragma unroll
            for (int i = 0; i < 8; ++i) {
                x0[i] = f0[(batch * 8 + i) * 64 + l];
                x1[i] = f1[(batch * 8 + i) * 64 + l];
            }
#pragma unroll
            for (int i = 0; i < 8; ++i) {
                const int ii = batch * 8 + i;
                const float qa0 = __shfl(q0, 2 * ii + (l >> 5), 64);
                const float qa1 = __shfl(q1, 2 * ii + (l >> 5), 64);
                a0.x = fmaf(qa0, x0[i].x, a0.x);
                a0.y = fmaf(qa0, x0[i].y, a0.y);
                a0.z = fmaf(qa0, x0[i].z, a0.z);
                a0.w = fmaf(qa0, x0[i].w, a0.w);
                a1.x = fmaf(qa1, x1[i].x, a1.x);
                a1.y = fmaf(qa1, x1[i].y, a1.y);
                a1.z = fmaf(qa1, x1[i].z, a1.z);
                a1.w = fmaf(qa1, x1[i].w, a1.w);
            }
        }
        // combine the two half-wave partials (a-parity split)
        a0.x += __shfl_xor(a0.x, 32, 64);
        a0.y += __shfl_xor(a0.y, 32, 64);
        a0.z += __shfl_xor(a0.z, 32, 64);
        a0.w += __shfl_xor(a0.w, 32, 64);
        a1.x += __shfl_xor(a1.x, 32, 64);
        a1.y += __shfl_xor(a1.y, 32, 64);
        a1.z += __shfl_xor(a1.z, 32, 64);
        a1.w += __shfl_xor(a1.w, 32, 64);
        if (l < 32) {
            *(float4*)(g_out + (size_t)r0 * Od + l * 4) = a0;
            *(float4*)(g_out + (size_t)(r0 + 1) * Od + l * 4) = a1;
        }
    }
}

__global__ __launch_bounds__(256, 8) void qatten_final(
    const float* __restrict__ g, const float* __restrict__ v,
    const float* __restrict__ bias, float* __restrict__ out)
{
    const int tid = threadIdx.x;
    const int b = blockIdx.x * 8 + (tid >> 5);
    const int i = tid & 31;
    const float4 gv = *(const float4*)(g + (size_t)b * Od + i * 4);
    const float4 vv = *(const float4*)(v + (size_t)b * Od + i * 4);
    float d = gv.x * vv.x;
    d = fmaf(gv.y, vv.y, d);
    d = fmaf(gv.z, vv.z, d);
    d = fmaf(gv.w, vv.w, d);
#pragma unroll
    for (int k = 16; k >= 1; k >>= 1) d += __shfl_down(d, k, 32);
    if (i == 0) out[b] = d + bias[b];
}

extern "C" void kernel_launch(void* const* d_in, const int* in_sizes, int n_in,
                              void* d_out, int out_size, void* d_ws, size_t ws_size,
                              hipStream_t stream) {
    const float* qv  = (const float*)d_in[0];
    const float* st  = (const float*)d_in[1];
    const float* fs  = (const float*)d_in[2];
    const float* Wq1 = (const float*)d_in[3];
    const float* bq1 = (const float*)d_in[4];
    const float* Wq2 = (const float*)d_in[5];
    const float* bq2 = (const float*)d_in[6];
    const float* Wk  = (const float*)d_in[7];
    const float* bk  = (const float*)d_in[8];
    const float* Wc1 = (const float*)d_in[9];
    const float* bc1 = (const float*)d_in[10];
    const float* Wc2 = (const float*)d_in[11];
    const float* bc2 = (const float*)d_in[12];
    float* out = (float*)d_out;

    // workspace (floats): WkT 8192 | bkSum 64 | bias 8192 | v 1048576 | g 1048576
    float* WkT   = (float*)d_ws;
    float* bkSum = WkT + QDd * Od;          // +8192
    float* bias  = bkSum + QDd;             // +64
    float* vbuf  = bias + 8192;             // +8192  (16-B aligned)
    float* gbuf  = vbuf + 8192 * Od;        // +1048576

    qatten_prep<<<32, 256, 0, stream>>>(Wk, bk, WkT, bkSum);
    qatten_main<<<A_BLOCKS + B_BLOCKS, 256, 0, stream>>>(
        qv, st, fs, Wq1, bq1, Wq2, bq2, Wc1, bc1, Wc2, bc2,
        WkT, bkSum, vbuf, bias, gbuf);
    qatten_final<<<1024, 256, 0, stream>>>(gbuf, vbuf, bias, out);
}